// Round 1
// baseline (378.650 us; speedup 1.0000x reference)
//
#include <hip/hip_runtime.h>

#define NN 10000
#define EE 160000
#define DD 1024          // D_IN + H
#define FOURH 2048
#define HH 512
#define MT 20000         // B*N
#define MPAD 20032       // 313 * 64
#define BSTRIDE 5120000  // N*512 elements per batch (x and h)

typedef __attribute__((ext_vector_type(8))) short bf16x8;
typedef __attribute__((ext_vector_type(4))) float f32x4;

typedef __attribute__((address_space(1))) void gvoid;
typedef __attribute__((address_space(3))) void lvoid;

__device__ inline void gload16(const void* g, void* l) {
    __builtin_amdgcn_global_load_lds((gvoid*)g, (lvoid*)l, 16, 0, 0);
}

__device__ inline unsigned short f2bf(float f) {
    unsigned u = __float_as_uint(f);
    u += 0x7fff + ((u >> 16) & 1);   // RNE
    return (unsigned short)(u >> 16);
}

__device__ inline float sigmoidf_(float x) {
    x = fminf(fmaxf(x, -30.f), 30.f);
    return 1.f / (1.f + __expf(-x));
}
__device__ inline float tanhf_(float x) {
    x = fminf(fmaxf(x, -15.f), 15.f);
    float e = __expf(2.f * x);
    return (e - 1.f) / (e + 1.f);
}

// ---------------- CSR build ----------------

__global__ void count_kernel(const int* __restrict__ dst, int* __restrict__ counts) {
    int e = blockIdx.x * blockDim.x + threadIdx.x;
    if (e < EE) atomicAdd(&counts[dst[e]], 1);
}

__global__ void scan_kernel(const int* __restrict__ counts, int* __restrict__ offsets,
                            int* __restrict__ cursor, float* __restrict__ dinv,
                            float* __restrict__ invdeg) {
    __shared__ int s[1024];
    int tid = threadIdx.x;
    int running = 0;
    if (tid == 0) offsets[0] = 0;
    for (int base = 0; base < NN; base += 1024) {
        int i = base + tid;
        int v = (i < NN) ? counts[i] : 0;
        s[tid] = v;
        __syncthreads();
        for (int off = 1; off < 1024; off <<= 1) {
            int t = (tid >= off) ? s[tid - off] : 0;
            __syncthreads();
            s[tid] += t;
            __syncthreads();
        }
        int incl = s[tid];
        if (i < NN) {
            offsets[i + 1] = running + incl;
            cursor[i] = running + incl - v;   // exclusive
            float deg = (float)(v + 1);
            dinv[i] = rsqrtf(deg);
            invdeg[i] = 1.0f / deg;
        }
        running += s[1023];
        __syncthreads();
    }
}

__global__ void fill_kernel(const int* __restrict__ src, const int* __restrict__ dst,
                            int* __restrict__ cursor, int* __restrict__ csr_src) {
    int e = blockIdx.x * blockDim.x + threadIdx.x;
    if (e < EE) {
        int p = atomicAdd(&cursor[dst[e]], 1);
        csr_src[p] = src[e];
    }
}

// ---------------- W transpose -> bf16 (Wt[j][k]) ----------------

__global__ __launch_bounds__(256) void wt_kernel(const float* __restrict__ W,
                                                 unsigned short* __restrict__ Wt) {
    __shared__ float tile[32][33];
    int k0 = blockIdx.x * 32;
    int j0 = blockIdx.y * 32;
    int tx = threadIdx.x & 31;
    int ty = threadIdx.x >> 5;   // 0..7
#pragma unroll
    for (int i = 0; i < 32; i += 8)
        tile[ty + i][tx] = W[(size_t)(k0 + ty + i) * FOURH + (j0 + tx)];
    __syncthreads();
#pragma unroll
    for (int i = 0; i < 32; i += 8)
        Wt[(size_t)(j0 + ty + i) * DD + (k0 + tx)] = f2bf(tile[tx][ty + i]);
}

__global__ void padzero_kernel(unsigned short* __restrict__ agg) {
    int idx = blockIdx.x * 256 + threadIdx.x;      // 32*256 = 8192 ushort4's
    ushort4* p = (ushort4*)(agg + (size_t)MT * DD);
    if (idx < 8192) p[idx] = make_ushort4(0, 0, 0, 0);
}

// ---------------- aggregation (both batches per block) ----------------

__global__ __launch_bounds__(256) void agg_kernel(
    const float* __restrict__ x, const float* __restrict__ h,
    const int* __restrict__ csr_src, const int* __restrict__ offsets,
    const float* __restrict__ dinv, const float* __restrict__ invdeg,
    unsigned short* __restrict__ agg)
{
    int n = blockIdx.x;
    int t = threadIdx.x;                 // dims 4t..4t+3
    const float* base0 = (t < 128) ? (x + 4 * t) : (h + (4 * t - 512));
    float a0x = 0, a0y = 0, a0z = 0, a0w = 0;
    float a1x = 0, a1y = 0, a1z = 0, a1w = 0;
    float dn = dinv[n];
    int beg = offsets[n], end = offsets[n + 1];
    for (int j = beg; j < end; ++j) {
        int s = csr_src[j];
        float w = dn * dinv[s];
        const float* p = base0 + (size_t)s * 512;
        float4 v0 = *(const float4*)p;
        float4 v1 = *(const float4*)(p + BSTRIDE);
        a0x += w * v0.x; a0y += w * v0.y; a0z += w * v0.z; a0w += w * v0.w;
        a1x += w * v1.x; a1y += w * v1.y; a1z += w * v1.z; a1w += w * v1.w;
    }
    float sw = invdeg[n];
    const float* p = base0 + (size_t)n * 512;
    float4 v0 = *(const float4*)p;
    float4 v1 = *(const float4*)(p + BSTRIDE);
    a0x += sw * v0.x; a0y += sw * v0.y; a0z += sw * v0.z; a0w += sw * v0.w;
    a1x += sw * v1.x; a1y += sw * v1.y; a1z += sw * v1.z; a1w += sw * v1.w;

    ushort4 o0, o1;
    o0.x = f2bf(a0x); o0.y = f2bf(a0y); o0.z = f2bf(a0z); o0.w = f2bf(a0w);
    o1.x = f2bf(a1x); o1.y = f2bf(a1y); o1.z = f2bf(a1z); o1.w = f2bf(a1w);
    *(ushort4*)(agg + (size_t)n * DD + 4 * t) = o0;            // batch 0
    *(ushort4*)(agg + (size_t)(NN + n) * DD + 4 * t) = o1;     // batch 1
}

// ---------------- GEMM + fused LSTM epilogue ----------------
// A: agg (MPAD x 1024 bf16). B: Wt (2048 x 1024 bf16, col-major of W).
// Block tile: 64 rows x 64 h (x4 gates interleaved: lds col c -> gate=c&3, h=h0+(c>>2)).

__global__ __launch_bounds__(256, 2) void gemm_lstm_kernel(
    const unsigned short* __restrict__ agg,
    const unsigned short* __restrict__ Wt,
    const float* __restrict__ bias,
    const float* __restrict__ c_cur,
    float* __restrict__ out)
{
    __shared__ unsigned short As[64 * 64];    // [row][k], k-bytes XOR ((row&7)<<4)
    __shared__ unsigned short Ws[256 * 64];   // [c][k],   k-bytes XOR ((c&7)<<4)

    const int tid = threadIdx.x;
    const int lane = tid & 63;
    const int wave = tid >> 6;
    const int waveM = wave >> 1;   // 0..1
    const int waveC = wave & 1;    // 0..1
    const int blockM = blockIdx.x; // 0..312
    const int h0 = blockIdx.y * 64;

    // staging descriptors (chunk -> row/col + swizzled k-byte)
    int aRow[2], aKb[2];
#pragma unroll
    for (int ca = 0; ca < 2; ++ca) {
        int o = (ca * 256 + tid) * 16;
        int row = o >> 7;
        aRow[ca] = row;
        aKb[ca] = (o & 127) ^ ((row & 7) << 4);
    }
    int wJ[8], wKb[8];
#pragma unroll
    for (int cw = 0; cw < 8; ++cw) {
        int o = (cw * 256 + tid) * 16;
        int c = o >> 7;
        wJ[cw] = (c & 3) * 512 + h0 + (c >> 2);
        wKb[cw] = (o & 127) ^ ((c & 7) << 4);
    }

    f32x4 acc[2][8];
#pragma unroll
    for (int i = 0; i < 2; ++i)
#pragma unroll
        for (int j = 0; j < 8; ++j) {
            f32x4 z = {0.f, 0.f, 0.f, 0.f};
            acc[i][j] = z;
        }

    for (int kt = 0; kt < 16; ++kt) {
        __syncthreads();
#pragma unroll
        for (int ca = 0; ca < 2; ++ca) {
            const unsigned short* g = agg + (size_t)(blockM * 64 + aRow[ca]) * DD
                                          + kt * 64 + (aKb[ca] >> 1);
            gload16(g, As + (size_t)(ca * 256 + wave * 64) * 8);
        }
#pragma unroll
        for (int cw = 0; cw < 8; ++cw) {
            const unsigned short* g = Wt + (size_t)wJ[cw] * DD + kt * 64 + (wKb[cw] >> 1);
            gload16(g, Ws + (size_t)(cw * 256 + wave * 64) * 8);
        }
        __syncthreads();
#pragma unroll
        for (int ksub = 0; ksub < 2; ++ksub) {
            const int kbyte = ksub * 64 + ((lane >> 4) * 16);
            bf16x8 aF[2];
#pragma unroll
            for (int mi = 0; mi < 2; ++mi) {
                int r = waveM * 32 + mi * 16 + (lane & 15);
                aF[mi] = *(const bf16x8*)((const char*)As + r * 128 + (kbyte ^ ((r & 7) << 4)));
            }
#pragma unroll
            for (int ci = 0; ci < 8; ++ci) {
                int c = waveC * 128 + ci * 16 + (lane & 15);
                bf16x8 bF = *(const bf16x8*)((const char*)Ws + c * 128 + (kbyte ^ ((c & 7) << 4)));
                acc[0][ci] = __builtin_amdgcn_mfma_f32_16x16x32_bf16(aF[0], bF, acc[0][ci], 0, 0, 0);
                acc[1][ci] = __builtin_amdgcn_mfma_f32_16x16x32_bf16(aF[1], bF, acc[1][ci], 0, 0, 0);
            }
        }
    }

    // epilogue: 4x4 lane-quad transpose (rows x gates), then LSTM math
    const int a = lane & 3;
#pragma unroll
    for (int mi = 0; mi < 2; ++mi) {
#pragma unroll
        for (int ci = 0; ci < 8; ++ci) {
            float v0 = acc[mi][ci][0], v1 = acc[mi][ci][1];
            float v2 = acc[mi][ci][2], v3 = acc[mi][ci][3];
            // level 1: xor 2  (swap reg-bit1 <-> lane-bit1)
            bool hi1 = (lane & 2) != 0;
            float s0 = hi1 ? v0 : v2;
            float s1 = hi1 ? v1 : v3;
            float r0 = __shfl_xor(s0, 2, 64);
            float r1 = __shfl_xor(s1, 2, 64);
            if (hi1) { v0 = r0; v1 = r1; } else { v2 = r0; v3 = r1; }
            // level 2: xor 1  (swap reg-bit0 <-> lane-bit0)
            bool hi0 = (lane & 1) != 0;
            float t0 = hi0 ? v0 : v1;
            float t1 = hi0 ? v2 : v3;
            float q0 = __shfl_xor(t0, 1, 64);
            float q1 = __shfl_xor(t1, 1, 64);
            if (hi0) { v0 = q0; v2 = q1; } else { v1 = q0; v3 = q1; }
            // v0..v3 = pre-bias conv for gates i,f,o,g at (row, h)
            int rl = waveM * 32 + mi * 16 + ((lane >> 4) << 2) + a;
            int m = blockM * 64 + rl;
            int hl = waveC * 32 + ci * 4 + ((lane & 15) >> 2);
            int hh = h0 + hl;
            if (m < MT) {
                float iv = sigmoidf_(v0 + bias[hh]);
                float fv = sigmoidf_(v1 + bias[512 + hh]);
                float ov = sigmoidf_(v2 + bias[1024 + hh]);
                float gv = tanhf_(v3 + bias[1536 + hh]);
                float cold = c_cur[(size_t)m * 512 + hh];
                float cnew = fv * cold + iv * gv;
                float hnew = ov * tanhf_(cnew);
                out[(size_t)m * 512 + hh] = hnew;
                out[(size_t)10240000 + (size_t)m * 512 + hh] = cnew;
            }
        }
    }
}

extern "C" void kernel_launch(void* const* d_in, const int* in_sizes, int n_in,
                              void* d_out, int out_size, void* d_ws, size_t ws_size,
                              hipStream_t stream) {
    const float* x    = (const float*)d_in[0];
    const float* h    = (const float*)d_in[1];
    const float* c    = (const float*)d_in[2];
    const int*   ei   = (const int*)d_in[3];
    const float* W    = (const float*)d_in[4];
    const float* bias = (const float*)d_in[5];
    float* out = (float*)d_out;
    (void)in_sizes; (void)n_in; (void)out_size; (void)ws_size;

    const int* src = ei;
    const int* dst = ei + EE;

    char* ws = (char*)d_ws;
    size_t off = 0;
    auto alloc = [&](size_t bytes) -> void* {
        void* p = ws + off;
        off = (off + bytes + 255) & ~(size_t)255;
        return p;
    };
    unsigned short* agg = (unsigned short*)alloc((size_t)MPAD * DD * 2);
    unsigned short* Wt  = (unsigned short*)alloc((size_t)FOURH * DD * 2);
    int*   counts  = (int*)alloc(NN * 4);
    int*   offsets = (int*)alloc((NN + 1) * 4);
    int*   cursor  = (int*)alloc(NN * 4);
    float* dinv    = (float*)alloc(NN * 4);
    float* invdeg  = (float*)alloc(NN * 4);
    int*   csr     = (int*)alloc(EE * 4);

    hipMemsetAsync(counts, 0, NN * 4, stream);
    count_kernel<<<(EE + 255) / 256, 256, 0, stream>>>(dst, counts);
    scan_kernel<<<1, 1024, 0, stream>>>(counts, offsets, cursor, dinv, invdeg);
    fill_kernel<<<(EE + 255) / 256, 256, 0, stream>>>(src, dst, cursor, csr);
    wt_kernel<<<dim3(32, 64), 256, 0, stream>>>(W, Wt);
    padzero_kernel<<<32, 256, 0, stream>>>(agg);
    agg_kernel<<<NN, 256, 0, stream>>>(x, h, csr, offsets, dinv, invdeg, agg);
    gemm_lstm_kernel<<<dim3(313, 8), 256, 0, stream>>>(agg, Wt, bias, c, out);
}

// Round 2
// 314.298 us; speedup vs baseline: 1.2047x; 1.2047x over previous
//
#include <hip/hip_runtime.h>

#define NN 10000
#define EE 160000
#define DD 1024          // D_IN + H
#define FOURH 2048
#define HH 512
#define MT 20000         // B*N
#define MPAD 20032       // 313 * 64

typedef __attribute__((ext_vector_type(8))) short bf16x8;
typedef __attribute__((ext_vector_type(4))) float f32x4;

typedef __attribute__((address_space(1))) void gvoid;
typedef __attribute__((address_space(3))) void lvoid;

__device__ inline void gload16(const void* g, void* l) {
    __builtin_amdgcn_global_load_lds((gvoid*)g, (lvoid*)l, 16, 0, 0);
}

__device__ inline unsigned short f2bf(float f) {
    unsigned u = __float_as_uint(f);
    u += 0x7fff + ((u >> 16) & 1);   // RNE
    return (unsigned short)(u >> 16);
}

__device__ inline float bflo(unsigned u) { return __uint_as_float(u << 16); }
__device__ inline float bfhi(unsigned u) { return __uint_as_float(u & 0xffff0000u); }

__device__ inline float sigmoidf_(float x) {
    x = fminf(fmaxf(x, -30.f), 30.f);
    return 1.f / (1.f + __expf(-x));
}
__device__ inline float tanhf_(float x) {
    x = fminf(fmaxf(x, -15.f), 15.f);
    float e = __expf(2.f * x);
    return (e - 1.f) / (e + 1.f);
}

// ---------------- CSR build ----------------

__global__ void count_kernel(const int* __restrict__ dst, int* __restrict__ counts) {
    int e = blockIdx.x * blockDim.x + threadIdx.x;
    if (e < EE) atomicAdd(&counts[dst[e]], 1);
}

__global__ void scan_kernel(const int* __restrict__ counts, int* __restrict__ offsets,
                            int* __restrict__ cursor, float* __restrict__ dinv,
                            float* __restrict__ invdeg) {
    __shared__ int s[1024];
    int tid = threadIdx.x;
    int running = 0;
    if (tid == 0) offsets[0] = 0;
    for (int base = 0; base < NN; base += 1024) {
        int i = base + tid;
        int v = (i < NN) ? counts[i] : 0;
        s[tid] = v;
        __syncthreads();
        for (int off = 1; off < 1024; off <<= 1) {
            int t = (tid >= off) ? s[tid - off] : 0;
            __syncthreads();
            s[tid] += t;
            __syncthreads();
        }
        int incl = s[tid];
        if (i < NN) {
            offsets[i + 1] = running + incl;
            cursor[i] = running + incl - v;   // exclusive
            float deg = (float)(v + 1);
            dinv[i] = rsqrtf(deg);
            invdeg[i] = 1.0f / deg;
        }
        running += s[1023];
        __syncthreads();
    }
}

__global__ void fill_kernel(const int* __restrict__ src, const int* __restrict__ dst,
                            int* __restrict__ cursor, int* __restrict__ csr_src) {
    int e = blockIdx.x * blockDim.x + threadIdx.x;
    if (e < EE) {
        int p = atomicAdd(&cursor[dst[e]], 1);
        csr_src[p] = src[e];
    }
}

// ---------------- x,h -> packed bf16 rows xhc[n][2048] ----------------
// layout per node n: [0..511]=x b0, [512..1023]=h b0, [1024..1535]=x b1, [1536..2047]=h b1

__global__ __launch_bounds__(256) void convert_kernel(
    const float* __restrict__ x, const float* __restrict__ h,
    unsigned short* __restrict__ xhc)
{
    int n = blockIdx.x;
    int t = threadIdx.x;
    int sec = t >> 6;        // 0..3
    int li = t & 63;         // 8 floats each
    const float* srcp;
    if (sec == 0)      srcp = x + (size_t)n * 512 + li * 8;
    else if (sec == 1) srcp = h + (size_t)n * 512 + li * 8;
    else if (sec == 2) srcp = x + (size_t)(NN + n) * 512 + li * 8;
    else               srcp = h + (size_t)(NN + n) * 512 + li * 8;
    float4 v0 = *(const float4*)srcp;
    float4 v1 = *(const float4*)(srcp + 4);
    uint4 o;
    o.x = f2bf(v0.x) | ((unsigned)f2bf(v0.y) << 16);
    o.y = f2bf(v0.z) | ((unsigned)f2bf(v0.w) << 16);
    o.z = f2bf(v1.x) | ((unsigned)f2bf(v1.y) << 16);
    o.w = f2bf(v1.z) | ((unsigned)f2bf(v1.w) << 16);
    *(uint4*)(xhc + (size_t)n * 2048 + t * 8) = o;
}

__global__ void padzero_kernel(unsigned short* __restrict__ agg) {
    int idx = blockIdx.x * 256 + threadIdx.x;      // 32*256 = 8192 ushort4's
    ushort4* p = (ushort4*)(agg + (size_t)MT * DD);
    if (idx < 8192) p[idx] = make_ushort4(0, 0, 0, 0);
}

// ---------------- aggregation (bf16 gather, fp32 accumulate) ----------------

__global__ __launch_bounds__(256) void agg_kernel(
    const unsigned short* __restrict__ xhc,
    const int* __restrict__ csr_src, const int* __restrict__ offsets,
    const float* __restrict__ dinv, const float* __restrict__ invdeg,
    unsigned short* __restrict__ agg)
{
    int n = blockIdx.x;
    int t = threadIdx.x;                 // 8 bf16 per thread of the 2048-wide row
    const unsigned short* base = xhc + t * 8;
    float a0 = 0, a1 = 0, a2 = 0, a3 = 0, a4 = 0, a5 = 0, a6 = 0, a7 = 0;
    float dn = dinv[n];
    int beg = offsets[n], end = offsets[n + 1];
    for (int j = beg; j < end; ++j) {
        int s = csr_src[j];
        float w = dn * dinv[s];
        uint4 v = *(const uint4*)(base + (size_t)s * 2048);
        a0 += w * bflo(v.x); a1 += w * bfhi(v.x);
        a2 += w * bflo(v.y); a3 += w * bfhi(v.y);
        a4 += w * bflo(v.z); a5 += w * bfhi(v.z);
        a6 += w * bflo(v.w); a7 += w * bfhi(v.w);
    }
    float sw = invdeg[n];
    {
        uint4 v = *(const uint4*)(base + (size_t)n * 2048);
        a0 += sw * bflo(v.x); a1 += sw * bfhi(v.x);
        a2 += sw * bflo(v.y); a3 += sw * bfhi(v.y);
        a4 += sw * bflo(v.z); a5 += sw * bfhi(v.z);
        a6 += sw * bflo(v.w); a7 += sw * bfhi(v.w);
    }
    uint4 o;
    o.x = f2bf(a0) | ((unsigned)f2bf(a1) << 16);
    o.y = f2bf(a2) | ((unsigned)f2bf(a3) << 16);
    o.z = f2bf(a4) | ((unsigned)f2bf(a5) << 16);
    o.w = f2bf(a6) | ((unsigned)f2bf(a7) << 16);
    int bsel = t >> 7;                   // batch
    int d = (t & 127) * 8;               // dim within 1024
    *(uint4*)(agg + ((size_t)(bsel * NN + n)) * DD + d) = o;
}

// ---------------- W transpose -> bf16 (Wt[j][k]) ----------------

__global__ __launch_bounds__(256) void wt_kernel(const float* __restrict__ W,
                                                 unsigned short* __restrict__ Wt) {
    __shared__ float tile[32][33];
    int k0 = blockIdx.x * 32;
    int j0 = blockIdx.y * 32;
    int tx = threadIdx.x & 31;
    int ty = threadIdx.x >> 5;   // 0..7
#pragma unroll
    for (int i = 0; i < 32; i += 8)
        tile[ty + i][tx] = W[(size_t)(k0 + ty + i) * FOURH + (j0 + tx)];
    __syncthreads();
#pragma unroll
    for (int i = 0; i < 32; i += 8)
        Wt[(size_t)(j0 + ty + i) * DD + (k0 + tx)] = f2bf(tile[tx][ty + i]);
}

// ---------------- GEMM + fused LSTM epilogue ----------------
// A: agg (MPAD x 1024 bf16). B: Wt (2048 x 1024 bf16, col-major of W).
// Block tile: 64 rows x 64 h (x4 gates interleaved: lds col c -> gate=c&3, h=h0+(c>>2)).

__global__ __launch_bounds__(256, 2) void gemm_lstm_kernel(
    const unsigned short* __restrict__ agg,
    const unsigned short* __restrict__ Wt,
    const float* __restrict__ bias,
    const float* __restrict__ c_cur,
    float* __restrict__ out)
{
    __shared__ unsigned short As[64 * 64];    // [row][k], k-bytes XOR ((row&7)<<4)
    __shared__ unsigned short Ws[256 * 64];   // [c][k],   k-bytes XOR ((c&7)<<4)

    const int tid = threadIdx.x;
    const int lane = tid & 63;
    const int wave = tid >> 6;
    const int waveM = wave >> 1;   // 0..1
    const int waveC = wave & 1;    // 0..1
    const int blockM = blockIdx.x; // 0..312
    const int h0 = blockIdx.y * 64;

    int aRow[2], aKb[2];
#pragma unroll
    for (int ca = 0; ca < 2; ++ca) {
        int o = (ca * 256 + tid) * 16;
        int row = o >> 7;
        aRow[ca] = row;
        aKb[ca] = (o & 127) ^ ((row & 7) << 4);
    }
    int wJ[8], wKb[8];
#pragma unroll
    for (int cw = 0; cw < 8; ++cw) {
        int o = (cw * 256 + tid) * 16;
        int c = o >> 7;
        wJ[cw] = (c & 3) * 512 + h0 + (c >> 2);
        wKb[cw] = (o & 127) ^ ((c & 7) << 4);
    }

    f32x4 acc[2][8];
#pragma unroll
    for (int i = 0; i < 2; ++i)
#pragma unroll
        for (int j = 0; j < 8; ++j) {
            f32x4 z = {0.f, 0.f, 0.f, 0.f};
            acc[i][j] = z;
        }

    for (int kt = 0; kt < 16; ++kt) {
        __syncthreads();
#pragma unroll
        for (int ca = 0; ca < 2; ++ca) {
            const unsigned short* g = agg + (size_t)(blockM * 64 + aRow[ca]) * DD
                                          + kt * 64 + (aKb[ca] >> 1);
            gload16(g, As + (size_t)(ca * 256 + wave * 64) * 8);
        }
#pragma unroll
        for (int cw = 0; cw < 8; ++cw) {
            const unsigned short* g = Wt + (size_t)wJ[cw] * DD + kt * 64 + (wKb[cw] >> 1);
            gload16(g, Ws + (size_t)(cw * 256 + wave * 64) * 8);
        }
        __syncthreads();
#pragma unroll
        for (int ksub = 0; ksub < 2; ++ksub) {
            const int kbyte = ksub * 64 + ((lane >> 4) * 16);
            bf16x8 aF[2];
#pragma unroll
            for (int mi = 0; mi < 2; ++mi) {
                int r = waveM * 32 + mi * 16 + (lane & 15);
                aF[mi] = *(const bf16x8*)((const char*)As + r * 128 + (kbyte ^ ((r & 7) << 4)));
            }
#pragma unroll
            for (int ci = 0; ci < 8; ++ci) {
                int c = waveC * 128 + ci * 16 + (lane & 15);
                bf16x8 bF = *(const bf16x8*)((const char*)Ws + c * 128 + (kbyte ^ ((c & 7) << 4)));
                acc[0][ci] = __builtin_amdgcn_mfma_f32_16x16x32_bf16(aF[0], bF, acc[0][ci], 0, 0, 0);
                acc[1][ci] = __builtin_amdgcn_mfma_f32_16x16x32_bf16(aF[1], bF, acc[1][ci], 0, 0, 0);
            }
        }
    }

    // epilogue: 4x4 lane-quad transpose (rows x gates), then LSTM math
    const int a = lane & 3;
#pragma unroll
    for (int mi = 0; mi < 2; ++mi) {
#pragma unroll
        for (int ci = 0; ci < 8; ++ci) {
            float v0 = acc[mi][ci][0], v1 = acc[mi][ci][1];
            float v2 = acc[mi][ci][2], v3 = acc[mi][ci][3];
            bool hi1 = (lane & 2) != 0;
            float s0 = hi1 ? v0 : v2;
            float s1 = hi1 ? v1 : v3;
            float r0 = __shfl_xor(s0, 2, 64);
            float r1 = __shfl_xor(s1, 2, 64);
            if (hi1) { v0 = r0; v1 = r1; } else { v2 = r0; v3 = r1; }
            bool hi0 = (lane & 1) != 0;
            float t0 = hi0 ? v0 : v1;
            float t1 = hi0 ? v2 : v3;
            float q0 = __shfl_xor(t0, 1, 64);
            float q1 = __shfl_xor(t1, 1, 64);
            if (hi0) { v0 = q0; v2 = q1; } else { v1 = q0; v3 = q1; }
            int rl = waveM * 32 + mi * 16 + ((lane >> 4) << 2) + a;
            int m = blockM * 64 + rl;
            int hl = waveC * 32 + ci * 4 + ((lane & 15) >> 2);
            int hh = h0 + hl;
            if (m < MT) {
                float iv = sigmoidf_(v0 + bias[hh]);
                float fv = sigmoidf_(v1 + bias[512 + hh]);
                float ov = sigmoidf_(v2 + bias[1024 + hh]);
                float gv = tanhf_(v3 + bias[1536 + hh]);
                float cold = c_cur[(size_t)m * 512 + hh];
                float cnew = fv * cold + iv * gv;
                float hnew = ov * tanhf_(cnew);
                out[(size_t)m * 512 + hh] = hnew;
                out[(size_t)10240000 + (size_t)m * 512 + hh] = cnew;
            }
        }
    }
}

extern "C" void kernel_launch(void* const* d_in, const int* in_sizes, int n_in,
                              void* d_out, int out_size, void* d_ws, size_t ws_size,
                              hipStream_t stream) {
    const float* x    = (const float*)d_in[0];
    const float* h    = (const float*)d_in[1];
    const float* c    = (const float*)d_in[2];
    const int*   ei   = (const int*)d_in[3];
    const float* W    = (const float*)d_in[4];
    const float* bias = (const float*)d_in[5];
    float* out = (float*)d_out;
    (void)in_sizes; (void)n_in; (void)out_size; (void)ws_size;

    const int* src = ei;
    const int* dst = ei + EE;

    char* ws = (char*)d_ws;
    size_t off = 0;
    auto alloc = [&](size_t bytes) -> void* {
        void* p = ws + off;
        off = (off + bytes + 255) & ~(size_t)255;
        return p;
    };
    unsigned short* agg = (unsigned short*)alloc((size_t)MPAD * DD * 2);
    unsigned short* Wt  = (unsigned short*)alloc((size_t)FOURH * DD * 2);
    unsigned short* xhc = (unsigned short*)alloc((size_t)NN * 2048 * 2);
    int*   counts  = (int*)alloc(NN * 4);
    int*   offsets = (int*)alloc((NN + 1) * 4);
    int*   cursor  = (int*)alloc(NN * 4);
    float* dinv    = (float*)alloc(NN * 4);
    float* invdeg  = (float*)alloc(NN * 4);
    int*   csr     = (int*)alloc(EE * 4);

    hipMemsetAsync(counts, 0, NN * 4, stream);
    count_kernel<<<(EE + 255) / 256, 256, 0, stream>>>(dst, counts);
    scan_kernel<<<1, 1024, 0, stream>>>(counts, offsets, cursor, dinv, invdeg);
    fill_kernel<<<(EE + 255) / 256, 256, 0, stream>>>(src, dst, cursor, csr);
    convert_kernel<<<NN, 256, 0, stream>>>(x, h, xhc);
    wt_kernel<<<dim3(32, 64), 256, 0, stream>>>(W, Wt);
    padzero_kernel<<<32, 256, 0, stream>>>(agg);
    agg_kernel<<<NN, 256, 0, stream>>>(xhc, csr, offsets, dinv, invdeg, agg);
    gemm_lstm_kernel<<<dim3(313, 8), 256, 0, stream>>>(agg, Wt, bias, c, out);
}

// Round 3
// 299.402 us; speedup vs baseline: 1.2647x; 1.0498x over previous
//
#include <hip/hip_runtime.h>

#define NN 10000
#define EE 160000
#define DD 1024          // D_IN + H
#define FOURH 2048
#define HH 512
#define MT 20000         // B*N
#define MPAD 20096       // 157 * 128

typedef __attribute__((ext_vector_type(8))) short bf16x8;
typedef __attribute__((ext_vector_type(4))) float f32x4;

typedef __attribute__((address_space(1))) void gvoid;
typedef __attribute__((address_space(3))) void lvoid;

__device__ inline void gload16(const void* g, void* l) {
    __builtin_amdgcn_global_load_lds((gvoid*)g, (lvoid*)l, 16, 0, 0);
}

__device__ inline unsigned short f2bf(float f) {
    unsigned u = __float_as_uint(f);
    u += 0x7fff + ((u >> 16) & 1);   // RNE
    return (unsigned short)(u >> 16);
}

__device__ inline float bflo(unsigned u) { return __uint_as_float(u << 16); }
__device__ inline float bfhi(unsigned u) { return __uint_as_float(u & 0xffff0000u); }

__device__ inline float sigmoidf_(float x) {
    x = fminf(fmaxf(x, -30.f), 30.f);
    return 1.f / (1.f + __expf(-x));
}
__device__ inline float tanhf_(float x) {
    x = fminf(fmaxf(x, -15.f), 15.f);
    float e = __expf(2.f * x);
    return (e - 1.f) / (e + 1.f);
}

// ---------------- CSR build ----------------

__global__ void count_kernel(const int* __restrict__ dst, int* __restrict__ counts) {
    int e = blockIdx.x * blockDim.x + threadIdx.x;
    if (e < EE) atomicAdd(&counts[dst[e]], 1);
}

__global__ void scan_kernel(const int* __restrict__ counts, int* __restrict__ offsets,
                            int* __restrict__ cursor, float* __restrict__ dinv,
                            float* __restrict__ invdeg) {
    __shared__ int s[1024];
    int tid = threadIdx.x;
    int running = 0;
    if (tid == 0) offsets[0] = 0;
    for (int base = 0; base < NN; base += 1024) {
        int i = base + tid;
        int v = (i < NN) ? counts[i] : 0;
        s[tid] = v;
        __syncthreads();
        for (int off = 1; off < 1024; off <<= 1) {
            int t = (tid >= off) ? s[tid - off] : 0;
            __syncthreads();
            s[tid] += t;
            __syncthreads();
        }
        int incl = s[tid];
        if (i < NN) {
            offsets[i + 1] = running + incl;
            cursor[i] = running + incl - v;   // exclusive
            float deg = (float)(v + 1);
            dinv[i] = rsqrtf(deg);
            invdeg[i] = 1.0f / deg;
        }
        running += s[1023];
        __syncthreads();
    }
}

__global__ void fill_kernel(const int* __restrict__ src, const int* __restrict__ dst,
                            int* __restrict__ cursor, int* __restrict__ csr_src) {
    int e = blockIdx.x * blockDim.x + threadIdx.x;
    if (e < EE) {
        int p = atomicAdd(&cursor[dst[e]], 1);
        csr_src[p] = src[e];
    }
}

// ---------------- x,h -> packed bf16 rows xhc[n][2048] ----------------

__global__ __launch_bounds__(256) void convert_kernel(
    const float* __restrict__ x, const float* __restrict__ h,
    unsigned short* __restrict__ xhc)
{
    int n = blockIdx.x;
    int t = threadIdx.x;
    int sec = t >> 6;        // 0..3
    int li = t & 63;         // 8 floats each
    const float* srcp;
    if (sec == 0)      srcp = x + (size_t)n * 512 + li * 8;
    else if (sec == 1) srcp = h + (size_t)n * 512 + li * 8;
    else if (sec == 2) srcp = x + (size_t)(NN + n) * 512 + li * 8;
    else               srcp = h + (size_t)(NN + n) * 512 + li * 8;
    float4 v0 = *(const float4*)srcp;
    float4 v1 = *(const float4*)(srcp + 4);
    uint4 o;
    o.x = f2bf(v0.x) | ((unsigned)f2bf(v0.y) << 16);
    o.y = f2bf(v0.z) | ((unsigned)f2bf(v0.w) << 16);
    o.z = f2bf(v1.x) | ((unsigned)f2bf(v1.y) << 16);
    o.w = f2bf(v1.z) | ((unsigned)f2bf(v1.w) << 16);
    *(uint4*)(xhc + (size_t)n * 2048 + t * 8) = o;
}

__global__ void padzero_kernel(unsigned short* __restrict__ agg) {
    int idx = blockIdx.x * 256 + threadIdx.x;      // 96 rows * 1024 / 4 = 24576 ushort4
    ushort4* p = (ushort4*)(agg + (size_t)MT * DD);
    if (idx < 24576) p[idx] = make_ushort4(0, 0, 0, 0);
}

// ---------------- aggregation (bf16 gather, fp32 accumulate) ----------------

__global__ __launch_bounds__(256) void agg_kernel(
    const unsigned short* __restrict__ xhc,
    const int* __restrict__ csr_src, const int* __restrict__ offsets,
    const float* __restrict__ dinv, const float* __restrict__ invdeg,
    unsigned short* __restrict__ agg)
{
    int n = blockIdx.x;
    int t = threadIdx.x;                 // 8 bf16 per thread of the 2048-wide row
    const unsigned short* base = xhc + t * 8;
    float a0 = 0, a1 = 0, a2 = 0, a3 = 0, a4 = 0, a5 = 0, a6 = 0, a7 = 0;
    float dn = dinv[n];
    int beg = offsets[n], end = offsets[n + 1];
    for (int j = beg; j < end; ++j) {
        int s = csr_src[j];
        float w = dn * dinv[s];
        uint4 v = *(const uint4*)(base + (size_t)s * 2048);
        a0 += w * bflo(v.x); a1 += w * bfhi(v.x);
        a2 += w * bflo(v.y); a3 += w * bfhi(v.y);
        a4 += w * bflo(v.z); a5 += w * bfhi(v.z);
        a6 += w * bflo(v.w); a7 += w * bfhi(v.w);
    }
    float sw = invdeg[n];
    {
        uint4 v = *(const uint4*)(base + (size_t)n * 2048);
        a0 += sw * bflo(v.x); a1 += sw * bfhi(v.x);
        a2 += sw * bflo(v.y); a3 += sw * bfhi(v.y);
        a4 += sw * bflo(v.z); a5 += sw * bfhi(v.z);
        a6 += sw * bflo(v.w); a7 += sw * bfhi(v.w);
    }
    uint4 o;
    o.x = f2bf(a0) | ((unsigned)f2bf(a1) << 16);
    o.y = f2bf(a2) | ((unsigned)f2bf(a3) << 16);
    o.z = f2bf(a4) | ((unsigned)f2bf(a5) << 16);
    o.w = f2bf(a6) | ((unsigned)f2bf(a7) << 16);
    int bsel = t >> 7;                   // batch
    int d = (t & 127) * 8;               // dim within 1024
    *(uint4*)(agg + ((size_t)(bsel * NN + n)) * DD + d) = o;
}

// ---------------- W transpose -> bf16 (Wt[j][k]) ----------------

__global__ __launch_bounds__(256) void wt_kernel(const float* __restrict__ W,
                                                 unsigned short* __restrict__ Wt) {
    __shared__ float tile[32][33];
    int k0 = blockIdx.x * 32;
    int j0 = blockIdx.y * 32;
    int tx = threadIdx.x & 31;
    int ty = threadIdx.x >> 5;   // 0..7
#pragma unroll
    for (int i = 0; i < 32; i += 8)
        tile[ty + i][tx] = W[(size_t)(k0 + ty + i) * FOURH + (j0 + tx)];
    __syncthreads();
#pragma unroll
    for (int i = 0; i < 32; i += 8)
        Wt[(size_t)(j0 + ty + i) * DD + (k0 + tx)] = f2bf(tile[tx][ty + i]);
}

// ---------------- GEMM + fused LSTM epilogue ----------------
// A: agg (MPAD x 1024 bf16). B: Wt (2048 x 1024 bf16, col-major of W).
// Block tile: 128 rows x 64 h (x4 gates interleaved: lds col c -> gate=c&3, h=h0+(c>>2)).
// 1D grid, bijective XCD-chunked swizzle (M-tile-major): each XCD owns contiguous M-range.

__global__ __launch_bounds__(256, 2) void gemm_lstm_kernel(
    const unsigned short* __restrict__ agg,
    const unsigned short* __restrict__ Wt,
    const float* __restrict__ bias,
    const float* __restrict__ c_cur,
    float* __restrict__ out)
{
    __shared__ char smem[48 * 1024];
    unsigned short* As = (unsigned short*)smem;            // [128][64], k-bytes XOR ((row&7)<<4)
    unsigned short* Ws = (unsigned short*)(smem + 16384);  // [256][64], k-bytes XOR ((c&7)<<4)
    float* fb = (float*)smem;                              // epilogue: [128][64] f32 (32KB)

    const int tid = threadIdx.x;
    const int lane = tid & 63;
    const int wave = tid >> 6;
    const int waveM = wave >> 1;   // 0..1
    const int waveC = wave & 1;    // 0..1

    const int orig = blockIdx.x;               // 1256 = 8 * 157
    const int f = (orig & 7) * 157 + (orig >> 3);
    const int blockM = f >> 3;                 // 0..156
    const int h0 = (f & 7) * 64;
    const int m0 = blockM * 128;

    // staging descriptors (chunk -> row/col + swizzled k-byte)
    int aRow[4], aKb[4];
#pragma unroll
    for (int ca = 0; ca < 4; ++ca) {
        int o = (ca * 256 + tid) * 16;
        int row = o >> 7;
        aRow[ca] = row;
        aKb[ca] = (o & 127) ^ ((row & 7) << 4);
    }
    int wJ[8], wKb[8];
#pragma unroll
    for (int cw = 0; cw < 8; ++cw) {
        int o = (cw * 256 + tid) * 16;
        int c = o >> 7;
        wJ[cw] = (c & 3) * 512 + h0 + (c >> 2);
        wKb[cw] = (o & 127) ^ ((c & 7) << 4);
    }

    f32x4 acc[4][8];
#pragma unroll
    for (int i = 0; i < 4; ++i)
#pragma unroll
        for (int j = 0; j < 8; ++j) {
            f32x4 z = {0.f, 0.f, 0.f, 0.f};
            acc[i][j] = z;
        }

    for (int kt = 0; kt < 16; ++kt) {
        __syncthreads();
#pragma unroll
        for (int ca = 0; ca < 4; ++ca) {
            const unsigned short* g = agg + (size_t)(m0 + aRow[ca]) * DD
                                          + kt * 64 + (aKb[ca] >> 1);
            gload16(g, As + (size_t)(ca * 256 + tid) * 8);
        }
#pragma unroll
        for (int cw = 0; cw < 8; ++cw) {
            const unsigned short* g = Wt + (size_t)wJ[cw] * DD + kt * 64 + (wKb[cw] >> 1);
            gload16(g, Ws + (size_t)(cw * 256 + tid) * 8);
        }
        __syncthreads();
#pragma unroll
        for (int ksub = 0; ksub < 2; ++ksub) {
            const int kbyte = ksub * 64 + ((lane >> 4) * 16);
            bf16x8 aF[4];
#pragma unroll
            for (int mi = 0; mi < 4; ++mi) {
                int r = waveM * 64 + mi * 16 + (lane & 15);
                aF[mi] = *(const bf16x8*)((const char*)As + r * 128 + (kbyte ^ ((r & 7) << 4)));
            }
#pragma unroll
            for (int ci = 0; ci < 8; ++ci) {
                int c = waveC * 128 + ci * 16 + (lane & 15);
                bf16x8 bF = *(const bf16x8*)((const char*)Ws + c * 128 + (kbyte ^ ((c & 7) << 4)));
#pragma unroll
                for (int mi = 0; mi < 4; ++mi)
                    acc[mi][ci] = __builtin_amdgcn_mfma_f32_16x16x32_bf16(aF[mi], bF, acc[mi][ci], 0, 0, 0);
            }
        }
    }

    // ---- epilogue: quad transpose -> LSTM math -> LDS-staged coalesced stores ----
    const int a = lane & 3;
    float cnewR[4][8];
    __syncthreads();   // all LDS (As/Ws) reads done; fb aliases them
#pragma unroll
    for (int mi = 0; mi < 4; ++mi) {
#pragma unroll
        for (int ci = 0; ci < 8; ++ci) {
            float v0 = acc[mi][ci][0], v1 = acc[mi][ci][1];
            float v2 = acc[mi][ci][2], v3 = acc[mi][ci][3];
            bool hi1 = (lane & 2) != 0;
            float s0 = hi1 ? v0 : v2;
            float s1 = hi1 ? v1 : v3;
            float r0 = __shfl_xor(s0, 2, 64);
            float r1 = __shfl_xor(s1, 2, 64);
            if (hi1) { v0 = r0; v1 = r1; } else { v2 = r0; v3 = r1; }
            bool hi0 = (lane & 1) != 0;
            float t0 = hi0 ? v0 : v1;
            float t1 = hi0 ? v2 : v3;
            float q0 = __shfl_xor(t0, 1, 64);
            float q1 = __shfl_xor(t1, 1, 64);
            if (hi0) { v0 = q0; v2 = q1; } else { v1 = q0; v3 = q1; }
            // v0..v3 = pre-bias conv for gates i,f,o,g at (row, h)
            int rl = waveM * 64 + mi * 16 + ((lane >> 4) << 2) + a;
            int hl = waveC * 32 + ci * 4 + ((lane & 15) >> 2);
            int m = m0 + rl;
            int hh = h0 + hl;
            float iv = sigmoidf_(v0 + bias[hh]);
            float fv = sigmoidf_(v1 + bias[512 + hh]);
            float ov = sigmoidf_(v2 + bias[1024 + hh]);
            float gv = tanhf_(v3 + bias[1536 + hh]);
            float cold = (m < MT) ? c_cur[(size_t)m * 512 + hh] : 0.f;
            float cnew = fv * cold + iv * gv;
            float hnew = ov * tanhf_(cnew);
            cnewR[mi][ci] = cnew;
            fb[rl * 64 + (hl ^ ((rl & 7) << 2))] = hnew;
        }
    }
    __syncthreads();
    // copy h: 128 rows x 64 floats, row-contiguous 16B stores
#pragma unroll
    for (int q = 0; q < 8; ++q) {
        int cid = q * 256 + tid;
        int row = cid >> 4;
        int c16 = cid & 15;
        int m = m0 + row;
        float4 v = *(const float4*)&fb[row * 64 + ((c16 * 4) ^ ((row & 7) << 2))];
        if (m < MT) *(float4*)&out[(size_t)m * 512 + h0 + c16 * 4] = v;
    }
    __syncthreads();
#pragma unroll
    for (int mi = 0; mi < 4; ++mi) {
#pragma unroll
        for (int ci = 0; ci < 8; ++ci) {
            int rl = waveM * 64 + mi * 16 + ((lane >> 4) << 2) + a;
            int hl = waveC * 32 + ci * 4 + ((lane & 15) >> 2);
            fb[rl * 64 + (hl ^ ((rl & 7) << 2))] = cnewR[mi][ci];
        }
    }
    __syncthreads();
#pragma unroll
    for (int q = 0; q < 8; ++q) {
        int cid = q * 256 + tid;
        int row = cid >> 4;
        int c16 = cid & 15;
        int m = m0 + row;
        float4 v = *(const float4*)&fb[row * 64 + ((c16 * 4) ^ ((row & 7) << 2))];
        if (m < MT) *(float4*)&out[(size_t)10240000 + (size_t)m * 512 + h0 + c16 * 4] = v;
    }
}

extern "C" void kernel_launch(void* const* d_in, const int* in_sizes, int n_in,
                              void* d_out, int out_size, void* d_ws, size_t ws_size,
                              hipStream_t stream) {
    const float* x    = (const float*)d_in[0];
    const float* h    = (const float*)d_in[1];
    const float* c    = (const float*)d_in[2];
    const int*   ei   = (const int*)d_in[3];
    const float* W    = (const float*)d_in[4];
    const float* bias = (const float*)d_in[5];
    float* out = (float*)d_out;
    (void)in_sizes; (void)n_in; (void)out_size; (void)ws_size;

    const int* src = ei;
    const int* dst = ei + EE;

    char* ws = (char*)d_ws;
    size_t off = 0;
    auto alloc = [&](size_t bytes) -> void* {
        void* p = ws + off;
        off = (off + bytes + 255) & ~(size_t)255;
        return p;
    };
    unsigned short* agg = (unsigned short*)alloc((size_t)MPAD * DD * 2);
    unsigned short* Wt  = (unsigned short*)alloc((size_t)FOURH * DD * 2);
    unsigned short* xhc = (unsigned short*)alloc((size_t)NN * 2048 * 2);
    int*   counts  = (int*)alloc(NN * 4);
    int*   offsets = (int*)alloc((NN + 1) * 4);
    int*   cursor  = (int*)alloc(NN * 4);
    float* dinv    = (float*)alloc(NN * 4);
    float* invdeg  = (float*)alloc(NN * 4);
    int*   csr     = (int*)alloc(EE * 4);

    hipMemsetAsync(counts, 0, NN * 4, stream);
    count_kernel<<<(EE + 255) / 256, 256, 0, stream>>>(dst, counts);
    scan_kernel<<<1, 1024, 0, stream>>>(counts, offsets, cursor, dinv, invdeg);
    fill_kernel<<<(EE + 255) / 256, 256, 0, stream>>>(src, dst, cursor, csr);
    convert_kernel<<<NN, 256, 0, stream>>>(x, h, xhc);
    wt_kernel<<<dim3(32, 64), 256, 0, stream>>>(W, Wt);
    padzero_kernel<<<96, 256, 0, stream>>>(agg);
    agg_kernel<<<NN, 256, 0, stream>>>(xhc, csr, offsets, dinv, invdeg, agg);
    gemm_lstm_kernel<<<1256, 256, 0, stream>>>(agg, Wt, bias, c, out);
}